// Round 12
// baseline (259.845 us; speedup 1.0000x reference)
//
#include <hip/hip_runtime.h>
#include <math.h>

// Problem constants (fixed by setup_inputs in the reference)
constexpr int B_ = 2, C_ = 64, H_ = 180, W_ = 360;
constexpr int HW = H_ * W_;             // 64800
constexpr int Hp = H_ + 2, Wp = W_ + 2; // padded dims 182 x 362
constexpr int O_ = 2 * C_;              // 128 velocity outputs

// 4-byte-aligned float4 (taps are 4 contiguous floats at dword alignment)
typedef float float4a __attribute__((ext_vector_type(4), aligned(4)));

// NOTE (round-5 lesson): the reference's seam mapping is DISCONTINUOUS in lon
// (remainder wraps + clamped 1-px-pad bicubic). Coordinate math must stay
// bit-close to fp32 libm: asinf/atan2f/exact-division remainder only.
__device__ __forceinline__ float frem(float x, float y) {
    return x - floorf(x / y) * y;            // IEEE division, matches jnp
}
// remainder(x, 2): x*0.5f is EXACT (pow2), floor identical to floor(x/2).
__device__ __forceinline__ float frem2(float x) {
    return x - floorf(x * 0.5f) * 2.0f;
}

// bicubic weights, A = -0.75
__device__ __forceinline__ float cub1(float x) {   // |t| <= 1
    return (1.25f * x - 2.25f) * x * x + 1.0f;
}
__device__ __forceinline__ float cub2(float x) {   // 1 < |t| < 2
    return ((-0.75f * x + 3.75f) * x - 6.0f) * x + 3.0f;
}

// Read geo_cyclic_pad(hidden,1)[y][x] directly from the unpadded image.
__device__ __forceinline__ float fetch_pad(const float* __restrict__ img, int y, int x) {
    int wc = x - 1;
    if (x == 0)      wc = W_ - 1;
    if (x == Wp - 1) wc = 0;
    int hh = y - 1;
    bool top = (y == 0), bot = (y == Hp - 1);
    if (top) hh = 0;
    if (bot) hh = H_ - 1;
    if (top || bot) { wc += W_ / 2; if (wc >= W_) wc -= W_; }
    return img[hh * W_ + wc];
}

struct Coord { float tx, ty; int jx, jy; };

// Departure point -> padded-image bicubic coordinates (EXACT r11 sequence).
__device__ __forceinline__ Coord compute_coord(
    float u, float v, float dt, float sp, float cp, float lon_p,
    float min_lat, float min_lon, float inv_dlat, float inv_dlon)
{
    const float two_pi = 6.28318530717958647f;
    const float sxw = (float)W_ / (float)Wp;
    const float syh = (float)H_ / (float)Hp;

    const float lon_pr = -u * dt;
    const float lat_pr = -v * dt;
    float slp, clp, slo, clo;
    __sincosf(lat_pr, &slp, &clp);
    __sincosf(lon_pr, &slo, &clo);
    float sin_lat = slp * cp + clp * clo * sp;
    sin_lat = fminf(fmaxf(sin_lat, -1.0f + 1e-7f), 1.0f - 1e-7f);
    const float lat = asinf(sin_lat);
    const float num = clp * slo;
    const float den = clp * clo * cp - slp * sp;
    const float lon = frem(lon_p + atan2f(num, den) + two_pi, two_pi);

    float gx = (lon - min_lon) * inv_dlon - 1.0f;
    float gy = (lat - min_lat) * inv_dlat - 1.0f;
    gx = frem2(gx + 1.0f) - 1.0f;
    const bool left  = (gx <= 0.0f);
    const bool outer = (fabsf(gy) > 1.0f);
    if (outer) gx += left ? 1.0f : -1.0f;
    if (gy < -1.0f)     gy = -(2.0f + gy);
    else if (gy > 1.0f) gy = 2.0f - gy;
    gx *= sxw;
    gy *= syh;

    const float ix = (gx + 1.0f) * 0.5f * (float)(Wp - 1);
    const float iy = (gy + 1.0f) * 0.5f * (float)(Hp - 1);
    const float fx0 = floorf(ix), fy0 = floorf(iy);
    Coord cr;
    cr.tx = ix - fx0; cr.ty = iy - fy0;
    cr.jx = (int)fx0; cr.jy = (int)fy0;
    return cr;
}

__device__ __forceinline__ bool is_interior(const Coord& cr) {
    return (cr.jx >= 2) & (cr.jx <= Wp - 4) & (cr.jy >= 2) & (cr.jy <= Hp - 4);
}

// Weighted reduce of 16 taps held in t[16].
__device__ __forceinline__ float bicubic_reduce(const float* t, float tx, float ty) {
    const float wx0 = cub2(tx + 1.0f), wx1 = cub1(tx);
    const float wx2 = cub1(1.0f - tx), wx3 = cub2(2.0f - tx);
    const float wy0 = cub2(ty + 1.0f), wy1 = cub1(ty);
    const float wy2 = cub1(1.0f - ty), wy3 = cub2(2.0f - ty);
    const float r0 = fmaf(wx3, t[3],  fmaf(wx2, t[2],  fmaf(wx1, t[1],  wx0 * t[0])));
    const float r1 = fmaf(wx3, t[7],  fmaf(wx2, t[6],  fmaf(wx1, t[5],  wx0 * t[4])));
    const float r2 = fmaf(wx3, t[11], fmaf(wx2, t[10], fmaf(wx1, t[9],  wx0 * t[8])));
    const float r3 = fmaf(wx3, t[15], fmaf(wx2, t[14], fmaf(wx1, t[13], wx0 * t[12])));
    return fmaf(wy3, r3, fmaf(wy2, r2, fmaf(wy1, r1, wy0 * r0)));
}

__device__ __forceinline__ void taps_interior(const float* __restrict__ img,
                                              const Coord& cr, float* t) {
    const float* __restrict__ p = img + (cr.jy - 2) * W_ + (cr.jx - 2);
#pragma unroll
    for (int r = 0; r < 4; ++r) {
        const float4a row = *(const float4a*)(p + r * W_);
        t[r * 4 + 0] = row.x; t[r * 4 + 1] = row.y;
        t[r * 4 + 2] = row.z; t[r * 4 + 3] = row.w;
    }
}

__device__ __forceinline__ void taps_border(const float* __restrict__ img,
                                            const Coord& cr, float* t) {
    int xs[4], ys[4];
#pragma unroll
    for (int r = 0; r < 4; ++r) {
        xs[r] = min(max(cr.jx - 1 + r, 0), Wp - 1);
        ys[r] = min(max(cr.jy - 1 + r, 0), Hp - 1);
    }
#pragma unroll
    for (int r = 0; r < 4; ++r)
#pragma unroll
        for (int cc = 0; cc < 4; ++cc)
            t[r * 4 + cc] = fetch_pad(img, ys[r], xs[cc]);
}

// Single-channel version (used by fallback kernel).
__device__ __forceinline__ float advect_one(
    const float* __restrict__ img, float u, float v, float dt,
    float sp, float cp, float lon_p,
    float min_lat, float min_lon, float inv_dlat, float inv_dlon)
{
    const Coord cr = compute_coord(u, v, dt, sp, cp, lon_p,
                                   min_lat, min_lon, inv_dlat, inv_dlon);
    float t[16];
    if (__all(is_interior(cr))) taps_interior(img, cr, t);
    else                        taps_border(img, cr, t);
    return bicubic_reduce(t, cr.tx, cr.ty);
}

// ---------------- Phase 1: uv = hidden x W_vel^T + b  (B,128,HW) ----------------
// r7-r10: four structurally different GEMMs all land at the same time ->
// vel is bound by its ~100 MB HBM round-trip, not its instruction stream.
constexpr int P1_PXT = 256;
constexpr int P1_OG  = 2;
constexpr int P1_OPG = O_ / P1_OG;      // 64 outputs per group
constexpr int P1_TILES = (HW + P1_PXT - 1) / P1_PXT; // 254

__global__ __launch_bounds__(P1_PXT, 4) void nsl_vel(
    const float* __restrict__ hidden, const float* __restrict__ W_vel,
    const float* __restrict__ b_vel, float* __restrict__ uv)
{
    const int bid  = blockIdx.x;
    const int tile = bid % P1_TILES;
    const int og   = (bid / P1_TILES) % P1_OG;
    const int b    = bid / (P1_TILES * P1_OG);
    const int px   = tile * P1_PXT + threadIdx.x;
    if (px >= HW) return;

    float acc[P1_OPG];
#pragma unroll
    for (int j = 0; j < P1_OPG; ++j) acc[j] = b_vel[og * P1_OPG + j];

    const float* hb = hidden + (size_t)b * C_ * HW + px;
    const float* Wg = W_vel + (size_t)og * P1_OPG * C_;

    float xf[4];
#pragma unroll
    for (int t = 0; t < 4; ++t) xf[t] = hb[(size_t)t * HW];

    for (int k0 = 0; k0 < C_; k0 += 4) {
        float xc[4];
#pragma unroll
        for (int t = 0; t < 4; ++t) xc[t] = xf[t];
        if (k0 + 4 < C_) {
#pragma unroll
            for (int t = 0; t < 4; ++t) xf[t] = hb[(size_t)(k0 + 4 + t) * HW];
        }
        // k-chain per output stays ascending -> bitwise-identical uv.
#pragma unroll
        for (int j = 0; j < P1_OPG; ++j) {
            const float* wr = Wg + (size_t)j * C_ + k0;
            acc[j] = fmaf(wr[0], xc[0], acc[j]);
            acc[j] = fmaf(wr[1], xc[1], acc[j]);
            acc[j] = fmaf(wr[2], xc[2], acc[j]);
            acc[j] = fmaf(wr[3], xc[3], acc[j]);
        }
    }

    float* o = uv + ((size_t)b * O_ + og * P1_OPG) * HW + px;
#pragma unroll
    for (int j = 0; j < P1_OPG; ++j) o[(size_t)j * HW] = acc[j];
}

// ---------------- Phase 2: ILP=2 — two channels (c, c+1) per thread ----------------
// r7-r11: advect pinned at ~120 us with VALUBusy ~50% -> half the time is
// dependency stall of ONE serial chain per thread. Two independent chains
// (shared pixel: lat/lon/sincos + scalars) interleave in the scheduler and
// fill each other's transcendental/tap-load stalls. Identical per-channel
// instruction sequence -> bitwise-identical output.
constexpr int P2_TILES = (HW + 255) / 256;   // 254

__global__ __launch_bounds__(256, 8) void nsl_advect2(
    const float* __restrict__ hidden,    // (B,C,H,W)
    const float* __restrict__ lat_grid,  // (B,H,W)
    const float* __restrict__ lon_grid,  // (B,H,W)
    const float* __restrict__ uv,        // (B,128,HW) from phase 1
    const float* __restrict__ dt_p,
    float* __restrict__ out)             // (B,C,H,W)
{
    const int px = blockIdx.x * 256 + threadIdx.x;
    if (px >= HW) return;
    const int yc = blockIdx.y;            // 0..63
    const int b  = yc >> 5;               // /32 channel-pairs
    const int c0 = (yc & 31) * 2;         // channels c0, c0+1

    const float dt      = dt_p[0];
    const float min_lat = lat_grid[0];
    const float max_lat = lat_grid[(H_ - 1) * W_];
    const float min_lon = lon_grid[0];
    const float max_lon = lon_grid[W_ - 1];
    const float inv_dlat = 2.0f / (max_lat - min_lat);
    const float inv_dlon = 2.0f / (max_lon - min_lon);

    const float lat_p = lat_grid[(size_t)b * HW + px];
    const float lon_p = lon_grid[(size_t)b * HW + px];
    float sp, cp;
    __sincosf(lat_p, &sp, &cp);

    const float u0 = uv[((size_t)b * O_ + c0) * HW + px];
    const float v0 = uv[((size_t)b * O_ + C_ + c0) * HW + px];
    const float u1 = uv[((size_t)b * O_ + c0 + 1) * HW + px];
    const float v1 = uv[((size_t)b * O_ + C_ + c0 + 1) * HW + px];

    // Two independent branch-free chains -> scheduler interleaves them.
    const Coord A = compute_coord(u0, v0, dt, sp, cp, lon_p,
                                  min_lat, min_lon, inv_dlat, inv_dlon);
    const Coord Bc = compute_coord(u1, v1, dt, sp, cp, lon_p,
                                   min_lat, min_lon, inv_dlat, inv_dlon);

    const float* __restrict__ img0 = hidden + ((size_t)b * C_ + c0) * HW;
    const float* __restrict__ img1 = img0 + HW;

    float t0[16], t1[16];
    if (__all(is_interior(A) & is_interior(Bc))) {
        taps_interior(img0, A, t0);       // 8 dwordx4 issued back-to-back:
        taps_interior(img1, Bc, t1);      // both tap sets' latency overlaps
    } else {
        taps_border(img0, A, t0);
        taps_border(img1, Bc, t1);
    }

    float* o = out + ((size_t)b * C_ + c0) * HW + px;
    o[0]  = bicubic_reduce(t0, A.tx, A.ty);
    o[HW] = bicubic_reduce(t1, Bc.tx, Bc.ty);
}

// ---------------- Fallback: fused kernel (round-6 structure, passing) ----------------
constexpr int FB_CG = 4, FB_CPT = C_ / FB_CG, FB_PXT = 256;
constexpr int FB_TILES = (HW + FB_PXT - 1) / FB_PXT;

__global__ __launch_bounds__(FB_PXT, 6) void nsl_fused(
    const float* __restrict__ hidden, const float* __restrict__ lat_grid,
    const float* __restrict__ lon_grid, const float* __restrict__ W_vel,
    const float* __restrict__ b_vel, const float* __restrict__ dt_p,
    float* __restrict__ out)
{
    const int bid  = blockIdx.x;
    const int tile = bid % FB_TILES;
    const int cg   = (bid / FB_TILES) % FB_CG;
    const int b    = bid / (FB_TILES * FB_CG);
    const int px   = tile * FB_PXT + threadIdx.x;
    if (px >= HW) return;

    const float dt      = dt_p[0];
    const float min_lat = lat_grid[0];
    const float max_lat = lat_grid[(H_ - 1) * W_];
    const float min_lon = lon_grid[0];
    const float max_lon = lon_grid[W_ - 1];
    const float inv_dlat = 2.0f / (max_lat - min_lat);
    const float inv_dlon = 2.0f / (max_lon - min_lon);

    const float lat_p = lat_grid[(size_t)b * HW + px];
    const float lon_p = lon_grid[(size_t)b * HW + px];
    float sp, cp;
    __sincosf(lat_p, &sp, &cp);

    float u[FB_CPT], v[FB_CPT];
#pragma unroll
    for (int i = 0; i < FB_CPT; ++i) {
        u[i] = b_vel[cg * FB_CPT + i];
        v[i] = b_vel[C_ + cg * FB_CPT + i];
    }
    const float* hb = hidden + (size_t)b * C_ * HW + px;
#pragma unroll 2
    for (int k = 0; k < C_; ++k) {
        const float x = hb[(size_t)k * HW];
#pragma unroll
        for (int i = 0; i < FB_CPT; ++i) {
            u[i] = fmaf(W_vel[(size_t)(cg * FB_CPT + i) * C_ + k], x, u[i]);
            v[i] = fmaf(W_vel[(size_t)(C_ + cg * FB_CPT + i) * C_ + k], x, v[i]);
        }
    }

    for (int i = 0; i < FB_CPT; ++i) {
        const int c = cg * FB_CPT + i;
        const float* __restrict__ img = hidden + ((size_t)b * C_ + c) * HW;
        out[((size_t)b * C_ + c) * HW + px] =
            advect_one(img, u[i], v[i], dt, sp, cp, lon_p,
                       min_lat, min_lon, inv_dlat, inv_dlon);
    }
}

extern "C" void kernel_launch(void* const* d_in, const int* in_sizes, int n_in,
                              void* d_out, int out_size, void* d_ws, size_t ws_size,
                              hipStream_t stream) {
    const float* hidden   = (const float*)d_in[0];
    const float* lat_grid = (const float*)d_in[1];
    const float* lon_grid = (const float*)d_in[2];
    const float* W_vel    = (const float*)d_in[3];
    const float* b_vel    = (const float*)d_in[4];
    const float* dt_p     = (const float*)d_in[5];
    float* out = (float*)d_out;

    const size_t uv_bytes = (size_t)B_ * O_ * HW * sizeof(float); // 66.4 MB
    if (ws_size >= uv_bytes) {
        float* uv = (float*)d_ws;
        nsl_vel<<<B_ * P1_OG * P1_TILES, P1_PXT, 0, stream>>>(hidden, W_vel, b_vel, uv);
        nsl_advect2<<<dim3(P2_TILES, B_ * C_ / 2), 256, 0, stream>>>(
            hidden, lat_grid, lon_grid, uv, dt_p, out);
    } else {
        nsl_fused<<<B_ * FB_CG * FB_TILES, FB_PXT, 0, stream>>>(
            hidden, lat_grid, lon_grid, W_vel, b_vel, dt_p, out);
    }
}

// Round 13
// 227.140 us; speedup vs baseline: 1.1440x; 1.1440x over previous
//
#include <hip/hip_runtime.h>
#include <math.h>

// Problem constants (fixed by setup_inputs in the reference)
constexpr int B_ = 2, C_ = 64, H_ = 180, W_ = 360;
constexpr int HW = H_ * W_;             // 64800
constexpr int Hp = H_ + 2, Wp = W_ + 2; // padded dims 182 x 362
constexpr int O_ = 2 * C_;              // 128 velocity outputs

// 4-byte-aligned float4 (taps are 4 contiguous floats at dword alignment)
typedef float float4a __attribute__((ext_vector_type(4), aligned(4)));

// NOTE (round-5 lesson): the reference's seam mapping is DISCONTINUOUS in lon
// (remainder wraps + clamped 1-px-pad bicubic). Coordinate math must stay
// bit-close to fp32 libm: asinf/atan2f/exact-division remainder only.
__device__ __forceinline__ float frem(float x, float y) {
    return x - floorf(x / y) * y;            // IEEE division, matches jnp
}
// remainder(x, 2): x*0.5f is EXACT (pow2), floor identical to floor(x/2).
__device__ __forceinline__ float frem2(float x) {
    return x - floorf(x * 0.5f) * 2.0f;
}

// bicubic weights, A = -0.75
__device__ __forceinline__ float cub1(float x) {   // |t| <= 1
    return (1.25f * x - 2.25f) * x * x + 1.0f;
}
__device__ __forceinline__ float cub2(float x) {   // 1 < |t| < 2
    return ((-0.75f * x + 3.75f) * x - 6.0f) * x + 3.0f;
}

// Read geo_cyclic_pad(hidden,1)[y][x] directly from the unpadded image.
__device__ __forceinline__ float fetch_pad(const float* __restrict__ img, int y, int x) {
    int wc = x - 1;
    if (x == 0)      wc = W_ - 1;
    if (x == Wp - 1) wc = 0;
    int hh = y - 1;
    bool top = (y == 0), bot = (y == Hp - 1);
    if (top) hh = 0;
    if (bot) hh = H_ - 1;
    if (top || bot) { wc += W_ / 2; if (wc >= W_) wc -= W_; }
    return img[hh * W_ + wc];
}

struct Coord { float tx, ty; int jx, jy; };

// Departure point -> padded-image bicubic coordinates (EXACT r11 sequence).
__device__ __forceinline__ Coord compute_coord(
    float u, float v, float dt, float sp, float cp, float lon_p,
    float min_lat, float min_lon, float inv_dlat, float inv_dlon)
{
    const float two_pi = 6.28318530717958647f;
    const float sxw = (float)W_ / (float)Wp;
    const float syh = (float)H_ / (float)Hp;

    const float lon_pr = -u * dt;
    const float lat_pr = -v * dt;
    float slp, clp, slo, clo;
    __sincosf(lat_pr, &slp, &clp);
    __sincosf(lon_pr, &slo, &clo);
    float sin_lat = slp * cp + clp * clo * sp;
    sin_lat = fminf(fmaxf(sin_lat, -1.0f + 1e-7f), 1.0f - 1e-7f);
    const float lat = asinf(sin_lat);
    const float num = clp * slo;
    const float den = clp * clo * cp - slp * sp;
    const float lon = frem(lon_p + atan2f(num, den) + two_pi, two_pi);

    float gx = (lon - min_lon) * inv_dlon - 1.0f;
    float gy = (lat - min_lat) * inv_dlat - 1.0f;
    gx = frem2(gx + 1.0f) - 1.0f;
    const bool left  = (gx <= 0.0f);
    const bool outer = (fabsf(gy) > 1.0f);
    if (outer) gx += left ? 1.0f : -1.0f;
    if (gy < -1.0f)     gy = -(2.0f + gy);
    else if (gy > 1.0f) gy = 2.0f - gy;
    gx *= sxw;
    gy *= syh;

    const float ix = (gx + 1.0f) * 0.5f * (float)(Wp - 1);
    const float iy = (gy + 1.0f) * 0.5f * (float)(Hp - 1);
    const float fx0 = floorf(ix), fy0 = floorf(iy);
    Coord cr;
    cr.tx = ix - fx0; cr.ty = iy - fy0;
    cr.jx = (int)fx0; cr.jy = (int)fy0;
    return cr;
}

__device__ __forceinline__ bool is_interior(const Coord& cr) {
    return (cr.jx >= 2) & (cr.jx <= Wp - 4) & (cr.jy >= 2) & (cr.jy <= Hp - 4);
}

// Weighted reduce of 16 taps held in t[16].
__device__ __forceinline__ float bicubic_reduce(const float* t, float tx, float ty) {
    const float wx0 = cub2(tx + 1.0f), wx1 = cub1(tx);
    const float wx2 = cub1(1.0f - tx), wx3 = cub2(2.0f - tx);
    const float wy0 = cub2(ty + 1.0f), wy1 = cub1(ty);
    const float wy2 = cub1(1.0f - ty), wy3 = cub2(2.0f - ty);
    const float r0 = fmaf(wx3, t[3],  fmaf(wx2, t[2],  fmaf(wx1, t[1],  wx0 * t[0])));
    const float r1 = fmaf(wx3, t[7],  fmaf(wx2, t[6],  fmaf(wx1, t[5],  wx0 * t[4])));
    const float r2 = fmaf(wx3, t[11], fmaf(wx2, t[10], fmaf(wx1, t[9],  wx0 * t[8])));
    const float r3 = fmaf(wx3, t[15], fmaf(wx2, t[14], fmaf(wx1, t[13], wx0 * t[12])));
    return fmaf(wy3, r3, fmaf(wy2, r2, fmaf(wy1, r1, wy0 * r0)));
}

__device__ __forceinline__ void taps_interior(const float* __restrict__ img,
                                              const Coord& cr, float* t) {
    const float* __restrict__ p = img + (cr.jy - 2) * W_ + (cr.jx - 2);
#pragma unroll
    for (int r = 0; r < 4; ++r) {
        const float4a row = *(const float4a*)(p + r * W_);
        t[r * 4 + 0] = row.x; t[r * 4 + 1] = row.y;
        t[r * 4 + 2] = row.z; t[r * 4 + 3] = row.w;
    }
}

__device__ __forceinline__ void taps_border(const float* __restrict__ img,
                                            const Coord& cr, float* t) {
    int xs[4], ys[4];
#pragma unroll
    for (int r = 0; r < 4; ++r) {
        xs[r] = min(max(cr.jx - 1 + r, 0), Wp - 1);
        ys[r] = min(max(cr.jy - 1 + r, 0), Hp - 1);
    }
#pragma unroll
    for (int r = 0; r < 4; ++r)
#pragma unroll
        for (int cc = 0; cc < 4; ++cc)
            t[r * 4 + cc] = fetch_pad(img, ys[r], xs[cc]);
}

// Single-channel advect (used by 2D kernel and fallback).
__device__ __forceinline__ float advect_one(
    const float* __restrict__ img, float u, float v, float dt,
    float sp, float cp, float lon_p,
    float min_lat, float min_lon, float inv_dlat, float inv_dlon)
{
    const Coord cr = compute_coord(u, v, dt, sp, cp, lon_p,
                                   min_lat, min_lon, inv_dlat, inv_dlon);
    float t[16];
    if (__all(is_interior(cr))) taps_interior(img, cr, t);
    else                        taps_border(img, cr, t);
    return bicubic_reduce(t, cr.tx, cr.ty);
}

// ---------------- Phase 1: uv = hidden x W_vel^T + b  (B,128,HW) ----------------
// r7-r10: four structurally different GEMMs all land at the same time ->
// vel is bound by its ~100 MB HBM round-trip, not its instruction stream.
constexpr int P1_PXT = 256;
constexpr int P1_OG  = 2;
constexpr int P1_OPG = O_ / P1_OG;      // 64 outputs per group
constexpr int P1_TILES = (HW + P1_PXT - 1) / P1_PXT; // 254

__global__ __launch_bounds__(P1_PXT, 4) void nsl_vel(
    const float* __restrict__ hidden, const float* __restrict__ W_vel,
    const float* __restrict__ b_vel, float* __restrict__ uv)
{
    const int bid  = blockIdx.x;
    const int tile = bid % P1_TILES;
    const int og   = (bid / P1_TILES) % P1_OG;
    const int b    = bid / (P1_TILES * P1_OG);
    const int px   = tile * P1_PXT + threadIdx.x;
    if (px >= HW) return;

    float acc[P1_OPG];
#pragma unroll
    for (int j = 0; j < P1_OPG; ++j) acc[j] = b_vel[og * P1_OPG + j];

    const float* hb = hidden + (size_t)b * C_ * HW + px;
    const float* Wg = W_vel + (size_t)og * P1_OPG * C_;

    float xf[4];
#pragma unroll
    for (int t = 0; t < 4; ++t) xf[t] = hb[(size_t)t * HW];

    for (int k0 = 0; k0 < C_; k0 += 4) {
        float xc[4];
#pragma unroll
        for (int t = 0; t < 4; ++t) xc[t] = xf[t];
        if (k0 + 4 < C_) {
#pragma unroll
            for (int t = 0; t < 4; ++t) xf[t] = hb[(size_t)(k0 + 4 + t) * HW];
        }
        // k-chain per output stays ascending -> bitwise-identical uv.
#pragma unroll
        for (int j = 0; j < P1_OPG; ++j) {
            const float* wr = Wg + (size_t)j * C_ + k0;
            acc[j] = fmaf(wr[0], xc[0], acc[j]);
            acc[j] = fmaf(wr[1], xc[1], acc[j]);
            acc[j] = fmaf(wr[2], xc[2], acc[j]);
            acc[j] = fmaf(wr[3], xc[3], acc[j]);
        }
    }

    float* o = uv + ((size_t)b * O_ + og * P1_OPG) * HW + px;
#pragma unroll
    for (int j = 0; j < P1_OPG; ++j) o[(size_t)j * HW] = acc[j];
}

// ---------------- Phase 2: 2D patch mapping ----------------
// r11 (fewer instrs: no change) + r12 (fewer waves: worse) exclude issue
// rate and chain latency; FETCH 164 MB vs ~100 MB ideal points at gather
// re-fetch. Wave = 16x4 pixel patch: the 4 patch rows' bicubic footprints
// OVERLAP (tap row r of py+1 == tap row r+1 of py), so the wave touches
// ~1/3 the cache lines and the 16x16 block tile reuses them in L1.
// Same pix -> same math -> bitwise-identical output.
constexpr int P2_TX = 16, P2_TY = 16;                 // block pixel tile
constexpr int P2_GX = (W_ + P2_TX - 1) / P2_TX;       // 23
constexpr int P2_GY = (H_ + P2_TY - 1) / P2_TY;       // 12

__global__ __launch_bounds__(256, 8) void nsl_advect_t(
    const float* __restrict__ hidden,    // (B,C,H,W)
    const float* __restrict__ lat_grid,  // (B,H,W)
    const float* __restrict__ lon_grid,  // (B,H,W)
    const float* __restrict__ uv,        // (B,128,HW) from phase 1
    const float* __restrict__ dt_p,
    float* __restrict__ out)             // (B,C,H,W)
{
    const int lane = threadIdx.x & 63;
    const int wv   = threadIdx.x >> 6;            // 0..3
    const int lx   = lane & 15;
    const int ly   = (lane >> 4) + wv * 4;        // wave = 16x4 patch
    const int px   = blockIdx.x * P2_TX + lx;
    const int py   = blockIdx.y * P2_TY + ly;
    if (px >= W_ || py >= H_) return;
    const int pix  = py * W_ + px;

    const int bc = blockIdx.z;          // b*C + c
    const int b  = bc >> 6;             // / C_
    const int c  = bc & (C_ - 1);

    const float dt      = dt_p[0];
    const float min_lat = lat_grid[0];
    const float max_lat = lat_grid[(H_ - 1) * W_];
    const float min_lon = lon_grid[0];
    const float max_lon = lon_grid[W_ - 1];
    const float inv_dlat = 2.0f / (max_lat - min_lat);
    const float inv_dlon = 2.0f / (max_lon - min_lon);

    const float lat_p = lat_grid[(size_t)b * HW + pix];
    const float lon_p = lon_grid[(size_t)b * HW + pix];
    float sp, cp;
    __sincosf(lat_p, &sp, &cp);

    const float u = uv[((size_t)b * O_ + c) * HW + pix];
    const float v = uv[((size_t)b * O_ + C_ + c) * HW + pix];

    const float* __restrict__ img = hidden + (size_t)bc * HW;
    out[(size_t)bc * HW + pix] = advect_one(img, u, v, dt, sp, cp, lon_p,
                                            min_lat, min_lon, inv_dlat, inv_dlon);
}

// ---------------- Fallback: fused kernel (round-6 structure, passing) ----------------
constexpr int FB_CG = 4, FB_CPT = C_ / FB_CG, FB_PXT = 256;
constexpr int FB_TILES = (HW + FB_PXT - 1) / FB_PXT;

__global__ __launch_bounds__(FB_PXT, 6) void nsl_fused(
    const float* __restrict__ hidden, const float* __restrict__ lat_grid,
    const float* __restrict__ lon_grid, const float* __restrict__ W_vel,
    const float* __restrict__ b_vel, const float* __restrict__ dt_p,
    float* __restrict__ out)
{
    const int bid  = blockIdx.x;
    const int tile = bid % FB_TILES;
    const int cg   = (bid / FB_TILES) % FB_CG;
    const int b    = bid / (FB_TILES * FB_CG);
    const int px   = tile * FB_PXT + threadIdx.x;
    if (px >= HW) return;

    const float dt      = dt_p[0];
    const float min_lat = lat_grid[0];
    const float max_lat = lat_grid[(H_ - 1) * W_];
    const float min_lon = lon_grid[0];
    const float max_lon = lon_grid[W_ - 1];
    const float inv_dlat = 2.0f / (max_lat - min_lat);
    const float inv_dlon = 2.0f / (max_lon - min_lon);

    const float lat_p = lat_grid[(size_t)b * HW + px];
    const float lon_p = lon_grid[(size_t)b * HW + px];
    float sp, cp;
    __sincosf(lat_p, &sp, &cp);

    float u[FB_CPT], v[FB_CPT];
#pragma unroll
    for (int i = 0; i < FB_CPT; ++i) {
        u[i] = b_vel[cg * FB_CPT + i];
        v[i] = b_vel[C_ + cg * FB_CPT + i];
    }
    const float* hb = hidden + (size_t)b * C_ * HW + px;
#pragma unroll 2
    for (int k = 0; k < C_; ++k) {
        const float x = hb[(size_t)k * HW];
#pragma unroll
        for (int i = 0; i < FB_CPT; ++i) {
            u[i] = fmaf(W_vel[(size_t)(cg * FB_CPT + i) * C_ + k], x, u[i]);
            v[i] = fmaf(W_vel[(size_t)(C_ + cg * FB_CPT + i) * C_ + k], x, v[i]);
        }
    }

    for (int i = 0; i < FB_CPT; ++i) {
        const int c = cg * FB_CPT + i;
        const float* __restrict__ img = hidden + ((size_t)b * C_ + c) * HW;
        out[((size_t)b * C_ + c) * HW + px] =
            advect_one(img, u[i], v[i], dt, sp, cp, lon_p,
                       min_lat, min_lon, inv_dlat, inv_dlon);
    }
}

extern "C" void kernel_launch(void* const* d_in, const int* in_sizes, int n_in,
                              void* d_out, int out_size, void* d_ws, size_t ws_size,
                              hipStream_t stream) {
    const float* hidden   = (const float*)d_in[0];
    const float* lat_grid = (const float*)d_in[1];
    const float* lon_grid = (const float*)d_in[2];
    const float* W_vel    = (const float*)d_in[3];
    const float* b_vel    = (const float*)d_in[4];
    const float* dt_p     = (const float*)d_in[5];
    float* out = (float*)d_out;

    const size_t uv_bytes = (size_t)B_ * O_ * HW * sizeof(float); // 66.4 MB
    if (ws_size >= uv_bytes) {
        float* uv = (float*)d_ws;
        nsl_vel<<<B_ * P1_OG * P1_TILES, P1_PXT, 0, stream>>>(hidden, W_vel, b_vel, uv);
        nsl_advect_t<<<dim3(P2_GX, P2_GY, B_ * C_), 256, 0, stream>>>(
            hidden, lat_grid, lon_grid, uv, dt_p, out);
    } else {
        nsl_fused<<<B_ * FB_CG * FB_TILES, FB_PXT, 0, stream>>>(
            hidden, lat_grid, lon_grid, W_vel, b_vel, dt_p, out);
    }
}

// Round 14
// 207.091 us; speedup vs baseline: 1.2547x; 1.0968x over previous
//
#include <hip/hip_runtime.h>
#include <math.h>

// Problem constants (fixed by setup_inputs in the reference)
constexpr int B_ = 2, C_ = 64, H_ = 180, W_ = 360;
constexpr int HW = H_ * W_;             // 64800
constexpr int Hp = H_ + 2, Wp = W_ + 2; // padded dims 182 x 362
constexpr int O_ = 2 * C_;              // 128 velocity outputs

// 4-byte-aligned float4 (taps are 4 contiguous floats at dword alignment)
typedef float float4a __attribute__((ext_vector_type(4), aligned(4)));

// NOTE (round-5 lesson): the reference's seam mapping is DISCONTINUOUS in lon
// (remainder wraps + clamped 1-px-pad bicubic). Coordinate math must stay
// bit-close to fp32 libm: asinf/atan2f/exact-division remainder only.
__device__ __forceinline__ float frem(float x, float y) {
    return x - floorf(x / y) * y;            // IEEE division, matches jnp
}
// remainder(x, 2): x*0.5f is EXACT (pow2), floor identical to floor(x/2).
__device__ __forceinline__ float frem2(float x) {
    return x - floorf(x * 0.5f) * 2.0f;
}

// bicubic weights, A = -0.75
__device__ __forceinline__ float cub1(float x) {   // |t| <= 1
    return (1.25f * x - 2.25f) * x * x + 1.0f;
}
__device__ __forceinline__ float cub2(float x) {   // 1 < |t| < 2
    return ((-0.75f * x + 3.75f) * x - 6.0f) * x + 3.0f;
}

// Read geo_cyclic_pad(hidden,1)[y][x] directly from the unpadded image.
__device__ __forceinline__ float fetch_pad(const float* __restrict__ img, int y, int x) {
    int wc = x - 1;
    if (x == 0)      wc = W_ - 1;
    if (x == Wp - 1) wc = 0;
    int hh = y - 1;
    bool top = (y == 0), bot = (y == Hp - 1);
    if (top) hh = 0;
    if (bot) hh = H_ - 1;
    if (top || bot) { wc += W_ / 2; if (wc >= W_) wc -= W_; }
    return img[hh * W_ + wc];
}

struct Coord { float tx, ty; int jx, jy; };

// Departure point -> padded-image bicubic coordinates (EXACT r11 sequence).
__device__ __forceinline__ Coord compute_coord(
    float u, float v, float dt, float sp, float cp, float lon_p,
    float min_lat, float min_lon, float inv_dlat, float inv_dlon)
{
    const float two_pi = 6.28318530717958647f;
    const float sxw = (float)W_ / (float)Wp;
    const float syh = (float)H_ / (float)Hp;

    const float lon_pr = -u * dt;
    const float lat_pr = -v * dt;
    float slp, clp, slo, clo;
    __sincosf(lat_pr, &slp, &clp);
    __sincosf(lon_pr, &slo, &clo);
    float sin_lat = slp * cp + clp * clo * sp;
    sin_lat = fminf(fmaxf(sin_lat, -1.0f + 1e-7f), 1.0f - 1e-7f);
    const float lat = asinf(sin_lat);
    const float num = clp * slo;
    const float den = clp * clo * cp - slp * sp;
    const float lon = frem(lon_p + atan2f(num, den) + two_pi, two_pi);

    float gx = (lon - min_lon) * inv_dlon - 1.0f;
    float gy = (lat - min_lat) * inv_dlat - 1.0f;
    gx = frem2(gx + 1.0f) - 1.0f;
    const bool left  = (gx <= 0.0f);
    const bool outer = (fabsf(gy) > 1.0f);
    if (outer) gx += left ? 1.0f : -1.0f;
    if (gy < -1.0f)     gy = -(2.0f + gy);
    else if (gy > 1.0f) gy = 2.0f - gy;
    gx *= sxw;
    gy *= syh;

    const float ix = (gx + 1.0f) * 0.5f * (float)(Wp - 1);
    const float iy = (gy + 1.0f) * 0.5f * (float)(Hp - 1);
    const float fx0 = floorf(ix), fy0 = floorf(iy);
    Coord cr;
    cr.tx = ix - fx0; cr.ty = iy - fy0;
    cr.jx = (int)fx0; cr.jy = (int)fy0;
    return cr;
}

__device__ __forceinline__ bool is_interior(const Coord& cr) {
    return (cr.jx >= 2) & (cr.jx <= Wp - 4) & (cr.jy >= 2) & (cr.jy <= Hp - 4);
}

// Weighted reduce of 16 taps held in t[16].
__device__ __forceinline__ float bicubic_reduce(const float* t, float tx, float ty) {
    const float wx0 = cub2(tx + 1.0f), wx1 = cub1(tx);
    const float wx2 = cub1(1.0f - tx), wx3 = cub2(2.0f - tx);
    const float wy0 = cub2(ty + 1.0f), wy1 = cub1(ty);
    const float wy2 = cub1(1.0f - ty), wy3 = cub2(2.0f - ty);
    const float r0 = fmaf(wx3, t[3],  fmaf(wx2, t[2],  fmaf(wx1, t[1],  wx0 * t[0])));
    const float r1 = fmaf(wx3, t[7],  fmaf(wx2, t[6],  fmaf(wx1, t[5],  wx0 * t[4])));
    const float r2 = fmaf(wx3, t[11], fmaf(wx2, t[10], fmaf(wx1, t[9],  wx0 * t[8])));
    const float r3 = fmaf(wx3, t[15], fmaf(wx2, t[14], fmaf(wx1, t[13], wx0 * t[12])));
    return fmaf(wy3, r3, fmaf(wy2, r2, fmaf(wy1, r1, wy0 * r0)));
}

__device__ __forceinline__ void taps_interior(const float* __restrict__ img,
                                              const Coord& cr, float* t) {
    const float* __restrict__ p = img + (cr.jy - 2) * W_ + (cr.jx - 2);
#pragma unroll
    for (int r = 0; r < 4; ++r) {
        const float4a row = *(const float4a*)(p + r * W_);
        t[r * 4 + 0] = row.x; t[r * 4 + 1] = row.y;
        t[r * 4 + 2] = row.z; t[r * 4 + 3] = row.w;
    }
}

__device__ __forceinline__ void taps_border(const float* __restrict__ img,
                                            const Coord& cr, float* t) {
    int xs[4], ys[4];
#pragma unroll
    for (int r = 0; r < 4; ++r) {
        xs[r] = min(max(cr.jx - 1 + r, 0), Wp - 1);
        ys[r] = min(max(cr.jy - 1 + r, 0), Hp - 1);
    }
#pragma unroll
    for (int r = 0; r < 4; ++r)
#pragma unroll
        for (int cc = 0; cc < 4; ++cc)
            t[r * 4 + cc] = fetch_pad(img, ys[r], xs[cc]);
}

// Single-channel advect (used by 2D kernel and fallback).
__device__ __forceinline__ float advect_one(
    const float* __restrict__ img, float u, float v, float dt,
    float sp, float cp, float lon_p,
    float min_lat, float min_lon, float inv_dlat, float inv_dlon)
{
    const Coord cr = compute_coord(u, v, dt, sp, cp, lon_p,
                                   min_lat, min_lon, inv_dlat, inv_dlon);
    float t[16];
    if (__all(is_interior(cr))) taps_interior(img, cr, t);
    else                        taps_border(img, cr, t);
    return bicubic_reduce(t, cr.tx, cr.ty);
}

// ---------------- Phase 1: uv = hidden x W_vel^T + b  (B,128,HW) ----------------
// r7-r10: four structurally different GEMMs all land at the same time ->
// vel is at its ~100 MB HBM round-trip floor (~55-70 us incl. launch).
constexpr int P1_PXT = 256;
constexpr int P1_OG  = 2;
constexpr int P1_OPG = O_ / P1_OG;      // 64 outputs per group
constexpr int P1_TILES = (HW + P1_PXT - 1) / P1_PXT; // 254

__global__ __launch_bounds__(P1_PXT, 4) void nsl_vel(
    const float* __restrict__ hidden, const float* __restrict__ W_vel,
    const float* __restrict__ b_vel, float* __restrict__ uv)
{
    const int bid  = blockIdx.x;
    const int tile = bid % P1_TILES;
    const int og   = (bid / P1_TILES) % P1_OG;
    const int b    = bid / (P1_TILES * P1_OG);
    const int px   = tile * P1_PXT + threadIdx.x;
    if (px >= HW) return;

    float acc[P1_OPG];
#pragma unroll
    for (int j = 0; j < P1_OPG; ++j) acc[j] = b_vel[og * P1_OPG + j];

    const float* hb = hidden + (size_t)b * C_ * HW + px;
    const float* Wg = W_vel + (size_t)og * P1_OPG * C_;

    float xf[4];
#pragma unroll
    for (int t = 0; t < 4; ++t) xf[t] = hb[(size_t)t * HW];

    for (int k0 = 0; k0 < C_; k0 += 4) {
        float xc[4];
#pragma unroll
        for (int t = 0; t < 4; ++t) xc[t] = xf[t];
        if (k0 + 4 < C_) {
#pragma unroll
            for (int t = 0; t < 4; ++t) xf[t] = hb[(size_t)(k0 + 4 + t) * HW];
        }
        // k-chain per output stays ascending -> bitwise-identical uv.
#pragma unroll
        for (int j = 0; j < P1_OPG; ++j) {
            const float* wr = Wg + (size_t)j * C_ + k0;
            acc[j] = fmaf(wr[0], xc[0], acc[j]);
            acc[j] = fmaf(wr[1], xc[1], acc[j]);
            acc[j] = fmaf(wr[2], xc[2], acc[j]);
            acc[j] = fmaf(wr[3], xc[3], acc[j]);
        }
    }

    float* o = uv + ((size_t)b * O_ + og * P1_OPG) * HW + px;
#pragma unroll
    for (int j = 0; j < P1_OPG; ++j) o[(size_t)j * HW] = acc[j];
}

// ---------------- Phase 2: XCD-localized 16x16 tiles, 16x4 wave patches --------
// r13 (patch mapping): -10 us but FETCH rose to 205 MB vs ~105 MB ideal ->
// cross-XCD L2 duplication: a channel slice's 276 blocks round-robin over all
// 8 XCDs, each XCD's L2 pulls its own copy from HBM (~4x hidden over-fetch,
// HBM-latency misses on the gather path). Fix (pure scheduling, bitwise-same
// math): flat grid decoded so xcd=id%8 and bc-major slots -> all 276 tiles of
// a bc run on ONE XCD; slice lives in that XCD's L2 (~0.5 MB active).
constexpr int P2_TX = 16, P2_TY = 16;                 // block pixel tile
constexpr int P2_GX = (W_ + P2_TX - 1) / P2_TX;       // 23
constexpr int P2_GY = (H_ + P2_TY - 1) / P2_TY;       // 12
constexpr int P2_NTILE = P2_GX * P2_GY;               // 276
constexpr int NXCD = 8;
constexpr int BC_PER_XCD = (B_ * C_) / NXCD;          // 16

__global__ __launch_bounds__(256, 8) void nsl_advect_x(
    const float* __restrict__ hidden,    // (B,C,H,W)
    const float* __restrict__ lat_grid,  // (B,H,W)
    const float* __restrict__ lon_grid,  // (B,H,W)
    const float* __restrict__ uv,        // (B,128,HW) from phase 1
    const float* __restrict__ dt_p,
    float* __restrict__ out)             // (B,C,H,W)
{
    // blockIdx -> (xcd, bc, tile): consecutive ids round-robin XCDs, so all
    // ids with id%8==x (and their bc range) execute on XCD x.
    const int id   = blockIdx.x;
    const int xcd  = id & (NXCD - 1);
    const int slot = id >> 3;                     // 0 .. 16*276-1
    const int bcl  = slot / P2_NTILE;             // 0..15 (block-uniform)
    const int tile = slot - bcl * P2_NTILE;       // 0..275
    const int bc   = xcd * BC_PER_XCD + bcl;      // b*C + c
    const int txx  = tile % P2_GX;
    const int tyy  = tile / P2_GX;

    const int lane = threadIdx.x & 63;
    const int wv   = threadIdx.x >> 6;            // 0..3
    const int lx   = lane & 15;
    const int ly   = (lane >> 4) + wv * 4;        // wave = 16x4 patch (r13 win)
    const int px   = txx * P2_TX + lx;
    const int py   = tyy * P2_TY + ly;
    if (px >= W_ || py >= H_) return;
    const int pix  = py * W_ + px;

    const int b  = bc >> 6;             // / C_
    const int c  = bc & (C_ - 1);

    const float dt      = dt_p[0];
    const float min_lat = lat_grid[0];
    const float max_lat = lat_grid[(H_ - 1) * W_];
    const float min_lon = lon_grid[0];
    const float max_lon = lon_grid[W_ - 1];
    const float inv_dlat = 2.0f / (max_lat - min_lat);
    const float inv_dlon = 2.0f / (max_lon - min_lon);

    const float lat_p = lat_grid[(size_t)b * HW + pix];
    const float lon_p = lon_grid[(size_t)b * HW + pix];
    float sp, cp;
    __sincosf(lat_p, &sp, &cp);

    const float u = uv[((size_t)b * O_ + c) * HW + pix];
    const float v = uv[((size_t)b * O_ + C_ + c) * HW + pix];

    const float* __restrict__ img = hidden + (size_t)bc * HW;
    out[(size_t)bc * HW + pix] = advect_one(img, u, v, dt, sp, cp, lon_p,
                                            min_lat, min_lon, inv_dlat, inv_dlon);
}

// ---------------- Fallback: fused kernel (round-6 structure, passing) ----------------
constexpr int FB_CG = 4, FB_CPT = C_ / FB_CG, FB_PXT = 256;
constexpr int FB_TILES = (HW + FB_PXT - 1) / FB_PXT;

__global__ __launch_bounds__(FB_PXT, 6) void nsl_fused(
    const float* __restrict__ hidden, const float* __restrict__ lat_grid,
    const float* __restrict__ lon_grid, const float* __restrict__ W_vel,
    const float* __restrict__ b_vel, const float* __restrict__ dt_p,
    float* __restrict__ out)
{
    const int bid  = blockIdx.x;
    const int tile = bid % FB_TILES;
    const int cg   = (bid / FB_TILES) % FB_CG;
    const int b    = bid / (FB_TILES * FB_CG);
    const int px   = tile * FB_PXT + threadIdx.x;
    if (px >= HW) return;

    const float dt      = dt_p[0];
    const float min_lat = lat_grid[0];
    const float max_lat = lat_grid[(H_ - 1) * W_];
    const float min_lon = lon_grid[0];
    const float max_lon = lon_grid[W_ - 1];
    const float inv_dlat = 2.0f / (max_lat - min_lat);
    const float inv_dlon = 2.0f / (max_lon - min_lon);

    const float lat_p = lat_grid[(size_t)b * HW + px];
    const float lon_p = lon_grid[(size_t)b * HW + px];
    float sp, cp;
    __sincosf(lat_p, &sp, &cp);

    float u[FB_CPT], v[FB_CPT];
#pragma unroll
    for (int i = 0; i < FB_CPT; ++i) {
        u[i] = b_vel[cg * FB_CPT + i];
        v[i] = b_vel[C_ + cg * FB_CPT + i];
    }
    const float* hb = hidden + (size_t)b * C_ * HW + px;
#pragma unroll 2
    for (int k = 0; k < C_; ++k) {
        const float x = hb[(size_t)k * HW];
#pragma unroll
        for (int i = 0; i < FB_CPT; ++i) {
            u[i] = fmaf(W_vel[(size_t)(cg * FB_CPT + i) * C_ + k], x, u[i]);
            v[i] = fmaf(W_vel[(size_t)(C_ + cg * FB_CPT + i) * C_ + k], x, v[i]);
        }
    }

    for (int i = 0; i < FB_CPT; ++i) {
        const int c = cg * FB_CPT + i;
        const float* __restrict__ img = hidden + ((size_t)b * C_ + c) * HW;
        out[((size_t)b * C_ + c) * HW + px] =
            advect_one(img, u[i], v[i], dt, sp, cp, lon_p,
                       min_lat, min_lon, inv_dlat, inv_dlon);
    }
}

extern "C" void kernel_launch(void* const* d_in, const int* in_sizes, int n_in,
                              void* d_out, int out_size, void* d_ws, size_t ws_size,
                              hipStream_t stream) {
    const float* hidden   = (const float*)d_in[0];
    const float* lat_grid = (const float*)d_in[1];
    const float* lon_grid = (const float*)d_in[2];
    const float* W_vel    = (const float*)d_in[3];
    const float* b_vel    = (const float*)d_in[4];
    const float* dt_p     = (const float*)d_in[5];
    float* out = (float*)d_out;

    const size_t uv_bytes = (size_t)B_ * O_ * HW * sizeof(float); // 66.4 MB
    if (ws_size >= uv_bytes) {
        float* uv = (float*)d_ws;
        nsl_vel<<<B_ * P1_OG * P1_TILES, P1_PXT, 0, stream>>>(hidden, W_vel, b_vel, uv);
        const int grid2 = NXCD * BC_PER_XCD * P2_NTILE;   // 35328
        nsl_advect_x<<<grid2, 256, 0, stream>>>(
            hidden, lat_grid, lon_grid, uv, dt_p, out);
    } else {
        nsl_fused<<<B_ * FB_CG * FB_TILES, FB_PXT, 0, stream>>>(
            hidden, lat_grid, lon_grid, W_vel, b_vel, dt_p, out);
    }
}